// Round 1
// baseline (2210.791 us; speedup 1.0000x reference)
//
#include <hip/hip_runtime.h>
#include <math.h>

#define B_    16
#define N_    512
#define D_    256
#define H_    8
#define DH_   32
#define DFF_  1024
#define L_    2
#define NEG_INF_ (-1e9f)
#define LRELU_ 0.2f

constexpr int BM = 64, BN = 64, BK = 16;

// ---------------- generic batched GEMM: C = act(scale * A @ B(^T) + bias) ----
// batch index z: zo = z / inner, zi = z % inner; ptr += zo*s?o + zi*s?i
template <bool TRANSB>
__global__ __launch_bounds__(256) void gemm_kernel(
    const float* __restrict__ Ag, const float* __restrict__ Bg,
    const float* __restrict__ bias, float* __restrict__ Cg,
    int M, int Nc, int K, int lda, int ldb, int ldc,
    int inner, long sAo, long sAi, long sBo, long sBi, long sCo, long sCi,
    float scale, int act)
{
    int z  = blockIdx.z;
    int zo = z / inner;
    int zi = z - zo * inner;
    const float* A  = Ag + (long)zo * sAo + (long)zi * sAi;
    const float* Bm = Bg + (long)zo * sBo + (long)zi * sBi;
    float*       C  = Cg + (long)zo * sCo + (long)zi * sCi;

    int bm = blockIdx.y * BM;
    int bn = blockIdx.x * BN;
    int tid = threadIdx.x;
    int tx = tid & 15, ty = tid >> 4;

    __shared__ float As[BK][BM + 1];
    __shared__ float Bs[BK][BN + 1];

    float acc[4][4] = {};

    for (int k0 = 0; k0 < K; k0 += BK) {
#pragma unroll
        for (int i = 0; i < 4; i++) {           // A tile: BM x BK -> As[k][m]
            int e = tid + i * 256;
            int r = e >> 4, c = e & 15;
            int gr = bm + r, gc = k0 + c;
            As[c][r] = (gr < M && gc < K) ? A[(long)gr * lda + gc] : 0.f;
        }
        if (TRANSB) {
#pragma unroll
            for (int i = 0; i < 4; i++) {       // B tile: BN rows x BK k -> Bs[k][n]
                int e = tid + i * 256;
                int r = e >> 4, c = e & 15;     // r: col j, c: k
                int gj = bn + r, gk = k0 + c;
                Bs[c][r] = (gj < Nc && gk < K) ? Bm[(long)gj * ldb + gk] : 0.f;
            }
        } else {
#pragma unroll
            for (int i = 0; i < 4; i++) {       // B tile: BK x BN -> Bs[k][n]
                int e = tid + i * 256;
                int r = e >> 6, c = e & 63;
                int gk = k0 + r, gc = bn + c;
                Bs[r][c] = (gk < K && gc < Nc) ? Bm[(long)gk * ldb + gc] : 0.f;
            }
        }
        __syncthreads();
#pragma unroll
        for (int kk = 0; kk < BK; kk++) {
            float a[4], b[4];
#pragma unroll
            for (int i = 0; i < 4; i++) a[i] = As[kk][ty * 4 + i];
#pragma unroll
            for (int j = 0; j < 4; j++) b[j] = Bs[kk][tx * 4 + j];
#pragma unroll
            for (int i = 0; i < 4; i++)
#pragma unroll
                for (int j = 0; j < 4; j++)
                    acc[i][j] += a[i] * b[j];
        }
        __syncthreads();
    }

#pragma unroll
    for (int i = 0; i < 4; i++) {
        int gr = bm + ty * 4 + i;
        if (gr >= M) continue;
#pragma unroll
        for (int j = 0; j < 4; j++) {
            int gc = bn + tx * 4 + j;
            if (gc >= Nc) continue;
            float v = acc[i][j] * scale;
            if (bias) v += bias[gc];
            if (act == 1) v = fmaxf(v, 0.f);
            else if (act == 2) v = v > 0.f ? v : (expf(v) - 1.f);   // ELU
            C[(long)gr * ldc + gc] = v;
        }
    }
}

static void gemm(hipStream_t st, bool transb,
                 const float* A, const float* Bm, const float* bias, float* C,
                 int M, int Nc, int K, int lda, int ldb, int ldc,
                 int batch, int inner,
                 long sAo, long sAi, long sBo, long sBi, long sCo, long sCi,
                 float scale, int act)
{
    dim3 grid((Nc + BN - 1) / BN, (M + BM - 1) / BM, batch);
    if (transb)
        gemm_kernel<true><<<grid, 256, 0, st>>>(A, Bm, bias, C, M, Nc, K, lda, ldb, ldc,
                                                inner, sAo, sAi, sBo, sBi, sCo, sCi, scale, act);
    else
        gemm_kernel<false><<<grid, 256, 0, st>>>(A, Bm, bias, C, M, Nc, K, lda, ldb, ldc,
                                                 inner, sAo, sAi, sBo, sBi, sCo, sCi, scale, act);
}

// ---------------- embedding gather: X[row,:] = embed[idx[row],:] -------------
__global__ __launch_bounds__(64) void gather_embed(const int* __restrict__ idx,
                                                   const float* __restrict__ embed,
                                                   float* __restrict__ X)
{
    int row = blockIdx.x;
    int id  = idx[row];
    const float4* src = (const float4*)(embed + (long)id * D_);
    float4*       dst = (float4*)(X + (long)row * D_);
    dst[threadIdx.x] = src[threadIdx.x];
}

// ---------------- GAT: s1 = h@a1, s2 = h@a2 (per row dot over 256) -----------
__global__ __launch_bounds__(64) void gat_s12(const float* __restrict__ h,
                                              const float* __restrict__ a1,
                                              const float* __restrict__ a2,
                                              float* __restrict__ s1,
                                              float* __restrict__ s2)
{
    int row  = blockIdx.x;
    int lane = threadIdx.x;
    const float4* h4  = (const float4*)(h + (long)row * D_);
    const float4* a14 = (const float4*)a1;
    const float4* a24 = (const float4*)a2;
    float4 hv = h4[lane], av = a14[lane], bv = a24[lane];
    float d1 = hv.x * av.x + hv.y * av.y + hv.z * av.z + hv.w * av.w;
    float d2 = hv.x * bv.x + hv.y * bv.y + hv.z * bv.z + hv.w * bv.w;
    for (int off = 32; off; off >>= 1) {
        d1 += __shfl_xor(d1, off);
        d2 += __shfl_xor(d2, off);
    }
    if (lane == 0) { s1[row] = d1; s2[row] = d2; }
}

// ---------------- GAT: alpha[row,:] = softmax(mask(leaky(s1_i + s2_j))) ------
__global__ __launch_bounds__(256) void gat_alpha(const float* __restrict__ s1,
                                                 const float* __restrict__ s2,
                                                 const int* __restrict__ edges,
                                                 float* __restrict__ alpha)
{
    int row = blockIdx.x;          // b*N + i
    int b   = row >> 9;            // / N_
    const int*   erow = edges + (long)row * N_;
    const float* s2b  = s2 + (long)b * N_;
    float si = s1[row];
    int t = threadIdx.x;

    float v0, v1;
    {
        float e = si + s2b[t];
        e = e > 0.f ? e : LRELU_ * e;
        v0 = (erow[t] > 0) ? e : NEG_INF_;
        int j = t + 256;
        float e2 = si + s2b[j];
        e2 = e2 > 0.f ? e2 : LRELU_ * e2;
        v1 = (erow[j] > 0) ? e2 : NEG_INF_;
    }
    __shared__ float redm[4], reds[4];
    float m = fmaxf(v0, v1);
    for (int off = 32; off; off >>= 1) m = fmaxf(m, __shfl_xor(m, off));
    if ((t & 63) == 0) redm[t >> 6] = m;
    __syncthreads();
    m = fmaxf(fmaxf(redm[0], redm[1]), fmaxf(redm[2], redm[3]));
    float e0 = expf(v0 - m), e1 = expf(v1 - m);
    float s = e0 + e1;
    for (int off = 32; off; off >>= 1) s += __shfl_xor(s, off);
    if ((t & 63) == 0) reds[t >> 6] = s;
    __syncthreads();
    s = reds[0] + reds[1] + reds[2] + reds[3];
    float inv = 1.f / s;
    alpha[(long)row * N_ + t]       = e0 * inv;
    alpha[(long)row * N_ + t + 256] = e1 * inv;
}

// ---------------- attention softmax rows (with additive int mask) ------------
__global__ __launch_bounds__(256) void attn_softmax(float* __restrict__ S,
                                                    const int* __restrict__ mask)
{
    long row = blockIdx.x;                 // (b*H + h)*N + i
    int  b   = (int)(row >> 12);           // / (H_*N_)
    float*     p    = S + row * N_;
    const int* mrow = mask + (long)b * N_;
    int t = threadIdx.x;

    float v0 = p[t]       + (float)mrow[t]       * NEG_INF_;
    float v1 = p[t + 256] + (float)mrow[t + 256] * NEG_INF_;

    __shared__ float redm[4], reds[4];
    float m = fmaxf(v0, v1);
    for (int off = 32; off; off >>= 1) m = fmaxf(m, __shfl_xor(m, off));
    if ((t & 63) == 0) redm[t >> 6] = m;
    __syncthreads();
    m = fmaxf(fmaxf(redm[0], redm[1]), fmaxf(redm[2], redm[3]));
    float e0 = expf(v0 - m), e1 = expf(v1 - m);
    float s = e0 + e1;
    for (int off = 32; off; off >>= 1) s += __shfl_xor(s, off);
    if ((t & 63) == 0) reds[t >> 6] = s;
    __syncthreads();
    s = reds[0] + reds[1] + reds[2] + reds[3];
    float inv = 1.f / s;
    p[t]       = e0 * inv;
    p[t + 256] = e1 * inv;
}

// ---------------- fused residual-add LayerNorm (row = 256) -------------------
__global__ __launch_bounds__(64) void ln_add(const float* __restrict__ x,
                                             const float* __restrict__ tm,
                                             const float* __restrict__ g,
                                             const float* __restrict__ bta,
                                             float* __restrict__ out)
{
    long row  = blockIdx.x;
    int  lane = threadIdx.x;
    const float4* x4 = (const float4*)(x + row * D_);
    const float4* t4 = (const float4*)(tm + row * D_);
    float4 xv = x4[lane], tv = t4[lane];
    float4 v = make_float4(xv.x + tv.x, xv.y + tv.y, xv.z + tv.z, xv.w + tv.w);
    float s = v.x + v.y + v.z + v.w;
    for (int off = 32; off; off >>= 1) s += __shfl_xor(s, off);
    float mean = s * (1.f / D_);
    float4 d = make_float4(v.x - mean, v.y - mean, v.z - mean, v.w - mean);
    float sq = d.x * d.x + d.y * d.y + d.z * d.z + d.w * d.w;
    for (int off = 32; off; off >>= 1) sq += __shfl_xor(sq, off);
    float var = sq * (1.f / D_);
    float rs = rsqrtf(var + 1e-6f);
    const float4* g4 = (const float4*)g;
    const float4* b4 = (const float4*)bta;
    float4 gv = g4[lane], bv = b4[lane];
    float4 o = make_float4(d.x * rs * gv.x + bv.x, d.y * rs * gv.y + bv.y,
                           d.z * rs * gv.z + bv.z, d.w * rs * gv.w + bv.w);
    ((float4*)(out + row * D_))[lane] = o;
}

// ---------------- x = x*sqrt(D) + positional encoding ------------------------
__global__ __launch_bounds__(256) void scale_pe(float* __restrict__ X)
{
    int row = blockIdx.x;            // b*N + n
    int n = row & (N_ - 1);
    int d = threadIdx.x;
    float expo = (float)(d & ~1) * (1.0f / D_);
    float inv  = powf(10000.0f, -expo);
    float ang  = (float)n * inv;
    float pe   = (d & 1) ? cosf(ang) : sinf(ang);
    long idx = (long)row * D_ + d;
    X[idx] = X[idx] * 16.0f + pe;    // sqrt(256) = 16
}

__global__ __launch_bounds__(256) void copy_f4(const float4* __restrict__ src,
                                               float4* __restrict__ dst, long n4)
{
    long i = (long)blockIdx.x * 256 + threadIdx.x;
    if (i < n4) dst[i] = src[i];
}

// ---------------- driver -----------------------------------------------------
extern "C" void kernel_launch(void* const* d_in, const int* in_sizes, int n_in,
                              void* d_out, int out_size, void* d_ws, size_t ws_size,
                              hipStream_t stream)
{
    const int*   node  = (const int*)d_in[0];
    const int*   edge  = (const int*)d_in[1];
    const int*   mask  = (const int*)d_in[2];
    const float* embed = (const float*)d_in[4];
    const float* Wg    = (const float*)d_in[5];
    const float* a1    = (const float*)d_in[6];
    const float* a2    = (const float*)d_in[7];
    const float* Wq    = (const float*)d_in[8];
    const float* bq    = (const float*)d_in[9];
    const float* Wk    = (const float*)d_in[10];
    const float* bk    = (const float*)d_in[11];
    const float* Wv    = (const float*)d_in[12];
    const float* bv    = (const float*)d_in[13];
    const float* Wo    = (const float*)d_in[14];
    const float* bo    = (const float*)d_in[15];
    const float* W1    = (const float*)d_in[16];
    const float* b1    = (const float*)d_in[17];
    const float* W2    = (const float*)d_in[18];
    const float* b2    = (const float*)d_in[19];
    const float* ln1g  = (const float*)d_in[20];
    const float* ln1b  = (const float*)d_in[21];
    const float* ln2g  = (const float*)d_in[22];
    const float* ln2b  = (const float*)d_in[23];

    const long XSZ = (long)B_ * N_ * D_;          // 2,097,152
    float* outx = (float*)d_out;
    float* ATT  = outx + XSZ;                     // B*H*N*N region (scratch until layer-1 softmax)

    float* ws = (float*)d_ws;
    float* X  = ws;                               // current activations
    float* Hb = X  + XSZ;                         // h / Wo-out / W2-out temp
    float* Qb = Hb + XSZ;
    float* Kb = Qb + XSZ;
    float* Vb = Kb + XSZ;
    float* Ob = Vb + XSZ;
    float* Fb = Qb;                               // FFN hidden (8.4M floats) aliases Q..O
    float* S1 = Ob + XSZ;
    float* S2 = S1 + B_ * N_;

    const int MR = B_ * N_;                       // 8192 rows

    // ---- embedding lookup ----
    gather_embed<<<MR, 64, 0, stream>>>(node, embed, X);

    // ---- GAT hops ----
    for (int hop = 0; hop < 2; hop++) {
        // h = X @ Wg
        gemm(stream, false, X, Wg, nullptr, Hb, MR, D_, D_, D_, D_, D_,
             1, 1, 0, 0, 0, 0, 0, 0, 1.f, 0);
        gat_s12<<<MR, 64, 0, stream>>>(Hb, a1, a2, S1, S2);
        gat_alpha<<<MR, 256, 0, stream>>>(S1, S2, edge, ATT);
        // X = elu(alpha @ h)   (batched over B)
        gemm(stream, false, ATT, Hb, nullptr, X, N_, D_, N_, N_, D_, D_,
             B_, 1, (long)N_ * N_, 0, (long)N_ * D_, 0, (long)N_ * D_, 0, 1.f, 2);
    }

    // ---- x = x*sqrt(D) + pe ----
    scale_pe<<<MR, 256, 0, stream>>>(X);

    const float rscale = 0.17677669529663687f;    // 1/sqrt(32)
    for (int l = 0; l < L_; l++) {
        const float* wq = Wq + (long)l * D_ * D_;
        const float* wk = Wk + (long)l * D_ * D_;
        const float* wv = Wv + (long)l * D_ * D_;
        const float* wo = Wo + (long)l * D_ * D_;
        const float* w1 = W1 + (long)l * D_ * DFF_;
        const float* w2 = W2 + (long)l * DFF_ * D_;

        gemm(stream, false, X, wq, bq + l * D_, Qb, MR, D_, D_, D_, D_, D_,
             1, 1, 0, 0, 0, 0, 0, 0, 1.f, 0);
        gemm(stream, false, X, wk, bk + l * D_, Kb, MR, D_, D_, D_, D_, D_,
             1, 1, 0, 0, 0, 0, 0, 0, 1.f, 0);
        gemm(stream, false, X, wv, bv + l * D_, Vb, MR, D_, D_, D_, D_, D_,
             1, 1, 0, 0, 0, 0, 0, 0, 1.f, 0);

        // scores = q @ k^T * 1/sqrt(dh)  -> ATT   (batched over B*H, NT)
        gemm(stream, true, Qb, Kb, nullptr, ATT, N_, N_, DH_, D_, D_, N_,
             B_ * H_, H_,
             (long)N_ * D_, DH_, (long)N_ * D_, DH_,
             (long)H_ * N_ * N_, (long)N_ * N_, rscale, 0);

        attn_softmax<<<B_ * H_ * N_, 256, 0, stream>>>(ATT, mask);

        // o = attn @ v  -> Ob (head-interleaved [B,N,D] layout)
        gemm(stream, false, ATT, Vb, nullptr, Ob, N_, DH_, N_, N_, D_, D_,
             B_ * H_, H_,
             (long)H_ * N_ * N_, (long)N_ * N_, (long)N_ * D_, DH_,
             (long)N_ * D_, DH_, 1.f, 0);

        // t = o @ Wo + bo ; x = LN(x + t)
        gemm(stream, false, Ob, wo, bo + l * D_, Hb, MR, D_, D_, D_, D_, D_,
             1, 1, 0, 0, 0, 0, 0, 0, 1.f, 0);
        ln_add<<<MR, 64, 0, stream>>>(X, Hb, ln1g + l * D_, ln1b + l * D_, X);

        // f = relu(x @ W1 + b1) ; t = f @ W2 + b2 ; x = LN(x + t)
        gemm(stream, false, X, w1, b1 + l * DFF_, Fb, MR, DFF_, D_, D_, DFF_, DFF_,
             1, 1, 0, 0, 0, 0, 0, 0, 1.f, 1);
        gemm(stream, false, Fb, w2, b2 + l * D_, Hb, MR, D_, DFF_, DFF_, D_, D_,
             1, 1, 0, 0, 0, 0, 0, 0, 1.f, 0);
        ln_add<<<MR, 64, 0, stream>>>(X, Hb, ln2g + l * D_, ln2b + l * D_, X);
    }

    // ---- write x output ----
    long n4 = XSZ / 4;
    copy_f4<<<(unsigned)((n4 + 255) / 256), 256, 0, stream>>>((const float4*)X,
                                                              (float4*)outx, n4);
}

// Round 2
// 765.458 us; speedup vs baseline: 2.8882x; 2.8882x over previous
//
#include <hip/hip_runtime.h>
#include <math.h>

#define B_    16
#define N_    512
#define D_    256
#define H_    8
#define DH_   32
#define DFF_  1024
#define L_    2
#define NEG_INF_ (-1e9f)
#define LRELU_ 0.2f

typedef __attribute__((ext_vector_type(8))) short bf8_t;
typedef __attribute__((ext_vector_type(4))) float f4_t;

__device__ __forceinline__ unsigned short f2bf(float f) {
    union { float f; unsigned u; } v; v.f = f;
    unsigned r = v.u + 0x7FFF + ((v.u >> 16) & 1);
    return (unsigned short)(r >> 16);
}
__device__ __forceinline__ float bf2f(unsigned short h) {
    union { unsigned u; float f; } v; v.u = ((unsigned)h) << 16;
    return v.f;
}

__device__ __forceinline__ void gl_lds16(const void* g, void* l) {
    __builtin_amdgcn_global_load_lds(
        (const __attribute__((address_space(1))) unsigned int*)g,
        (__attribute__((address_space(3))) unsigned int*)l, 16, 0, 0);
}

// ============ bf16 MFMA GEMM: C = act(scale * A @ Bt^T + bias) ==============
// A: [M x K] bf16 row-major (or f32 if CONVA, converted during staging)
// Bt: [N x K] bf16 row-major (i.e. B^T, k contiguous)
// out: Cf (f32) and/or Ch (bf16); trans=1 -> Ch[col*ldc + row] (bf16 only)
// batch z: zo = z/inner, zi = z%inner; ptr += zo*s?o + zi*s?i (element strides)
// Requires: M % BM == 0 (per batch), gridDim.x*BN == N, K % 32 == 0.
template <int BM, int BN, int WROWS, int WCOLS, bool CONVA>
__global__ __launch_bounds__(256) void mfma_gemm(
    const void* __restrict__ Ag_, const unsigned short* __restrict__ Btg,
    const float* __restrict__ bias,
    float* __restrict__ Cfg, unsigned short* __restrict__ Chg, int trans,
    int K, int lda, int ldb, int ldc,
    int inner, long sAo, long sAi, long sBo, long sBi, long sCo, long sCi,
    float scale, int act)
{
    constexpr int TM = BM / WROWS, TN = BN / WCOLS;
    constexpr int MT = TM / 16, NT = TN / 16;

    int z  = blockIdx.z;
    int zo = z / inner;
    int zi = z - zo * inner;
    const unsigned short* Ab = nullptr;
    const float*          Af = nullptr;
    if (CONVA) Af = (const float*)Ag_ + (long)zo * sAo + (long)zi * sAi;
    else       Ab = (const unsigned short*)Ag_ + (long)zo * sAo + (long)zi * sAi;
    const unsigned short* Bt = Btg + (long)zo * sBo + (long)zi * sBi;
    long co = (long)zo * sCo + (long)zi * sCi;

    int bm = blockIdx.y * BM;
    int bn = blockIdx.x * BN;
    int tid  = threadIdx.x;
    int lane = tid & 63;
    int w    = tid >> 6;
    int wr   = w / WCOLS, wc = w - wr * WCOLS;

    __shared__ unsigned short As[BM * 32];
    __shared__ unsigned short Bs[BN * 32];

    f4_t acc[MT][NT] = {};

    int lrow = lane & 15;
    int koff = (lane >> 4) * 8;

    for (int k0 = 0; k0 < K; k0 += 32) {
        if constexpr (!CONVA) {
#pragma unroll
            for (int t = w; t < BM / 16; t += 4) {
                int s = t * 512 + lane * 8;
                int r = s >> 5, c = s & 31;
                gl_lds16(Ab + (long)(bm + r) * lda + k0 + c, &As[t * 512]);
            }
        } else {
#pragma unroll
            for (int it = 0; it < BM / 128; it++) {
                int s = (it * 256 + tid) * 16;
                int r = s >> 5, c = s & 31;
                const float* src = Af + (long)(bm + r) * lda + k0 + c;
#pragma unroll
                for (int i = 0; i < 4; i++) {
                    float4 fv = *(const float4*)(src + i * 4);
                    ushort4 u = make_ushort4(f2bf(fv.x), f2bf(fv.y), f2bf(fv.z), f2bf(fv.w));
                    *(ushort4*)&As[s + i * 4] = u;
                }
            }
        }
#pragma unroll
        for (int t = w; t < BN / 16; t += 4) {
            int s = t * 512 + lane * 8;
            int r = s >> 5, c = s & 31;
            gl_lds16(Bt + (long)(bn + r) * ldb + k0 + c, &Bs[t * 512]);
        }
        __syncthreads();

        bf8_t af[MT], bfr[NT];
#pragma unroll
        for (int mi = 0; mi < MT; mi++)
            af[mi] = *(const bf8_t*)&As[(wr * TM + mi * 16 + lrow) * 32 + koff];
#pragma unroll
        for (int ni = 0; ni < NT; ni++)
            bfr[ni] = *(const bf8_t*)&Bs[(wc * TN + ni * 16 + lrow) * 32 + koff];
#pragma unroll
        for (int mi = 0; mi < MT; mi++)
#pragma unroll
            for (int ni = 0; ni < NT; ni++)
                acc[mi][ni] = __builtin_amdgcn_mfma_f32_16x16x32_bf16(
                    af[mi], bfr[ni], acc[mi][ni], 0, 0, 0);
        __syncthreads();
    }

#pragma unroll
    for (int mi = 0; mi < MT; mi++) {
#pragma unroll
        for (int ni = 0; ni < NT; ni++) {
            int row0 = bm + wr * TM + mi * 16 + (lane >> 4) * 4;
            int col  = bn + wc * TN + ni * 16 + (lane & 15);
            float bv = bias ? bias[col] : 0.f;
            float vv[4];
#pragma unroll
            for (int r = 0; r < 4; r++) {
                float v = acc[mi][ni][r] * scale + bv;
                if (act == 1) v = fmaxf(v, 0.f);
                else if (act == 2) v = v > 0.f ? v : (expf(v) - 1.f);
                vv[r] = v;
            }
            if (trans) {
                ushort4 u = make_ushort4(f2bf(vv[0]), f2bf(vv[1]), f2bf(vv[2]), f2bf(vv[3]));
                *(ushort4*)&Chg[co + (long)col * ldc + row0] = u;
            } else {
                if (Cfg) {
#pragma unroll
                    for (int r = 0; r < 4; r++)
                        Cfg[co + (long)(row0 + r) * ldc + col] = vv[r];
                }
                if (Chg) {
#pragma unroll
                    for (int r = 0; r < 4; r++)
                        Chg[co + (long)(row0 + r) * ldc + col] = f2bf(vv[r]);
                }
            }
        }
    }
}

// ============ weight transpose + f32->bf16 conversion ========================
struct ConvJobs {
    const float* src[13];
    unsigned short* dst[13];
    int R[13];
    int C[13];
};

__global__ __launch_bounds__(256) void conv_transpose(ConvJobs j)
{
    int z = blockIdx.z;
    int R = j.R[z], C = j.C[z];
    int r0 = blockIdx.y * 64, c0 = blockIdx.x * 64;
    if (r0 >= R || c0 >= C) return;
    __shared__ float t[64][65];
    const float* src = j.src[z];
    unsigned short* dst = j.dst[z];
    int tx = threadIdx.x & 63, ty = threadIdx.x >> 6;
#pragma unroll
    for (int i = 0; i < 16; i++) {
        int r = ty + i * 4;
        t[r][tx] = src[(long)(r0 + r) * C + c0 + tx];
    }
    __syncthreads();
#pragma unroll
    for (int i = 0; i < 16; i++) {
        int c = ty + i * 4;
        dst[(long)(c0 + c) * R + r0 + tx] = f2bf(t[tx][c]);
    }
}

// ============ embedding gather -> X f32 + Xb bf16 ============================
__global__ __launch_bounds__(64) void gather_embed(const int* __restrict__ idx,
                                                   const float* __restrict__ embed,
                                                   float* __restrict__ X,
                                                   unsigned short* __restrict__ Xb)
{
    int row = blockIdx.x;
    int id  = idx[row];
    float4 v = ((const float4*)(embed + (long)id * D_))[threadIdx.x];
    ((float4*)(X + (long)row * D_))[threadIdx.x] = v;
    ((ushort4*)(Xb + (long)row * D_))[threadIdx.x] =
        make_ushort4(f2bf(v.x), f2bf(v.y), f2bf(v.z), f2bf(v.w));
}

// ============ GAT s1/s2 from transposed h (bf16 [D][B*N]) ====================
__global__ __launch_bounds__(256) void gat_s12T(const unsigned short* __restrict__ hT,
                                                const float* __restrict__ a1,
                                                const float* __restrict__ a2,
                                                float* __restrict__ s1,
                                                float* __restrict__ s2)
{
    int j = blockIdx.x * 256 + threadIdx.x;   // token 0..8191
    float d1 = 0.f, d2 = 0.f;
    for (int d = 0; d < D_; d++) {
        float hv = bf2f(hT[(long)d * (B_ * N_) + j]);
        d1 += hv * a1[d];
        d2 += hv * a2[d];
    }
    s1[j] = d1;
    s2[j] = d2;
}

// ============ GAT softmax row -> bf16 alpha ==================================
__global__ __launch_bounds__(256) void gat_alpha(const float* __restrict__ s1,
                                                 const float* __restrict__ s2,
                                                 const int* __restrict__ edges,
                                                 unsigned short* __restrict__ alpha)
{
    int row = blockIdx.x;          // b*N + i
    int b   = row >> 9;
    const int*   erow = edges + (long)row * N_;
    const float* s2b  = s2 + (long)b * N_;
    float si = s1[row];
    int t = threadIdx.x;

    float e  = si + s2b[t];
    e = e > 0.f ? e : LRELU_ * e;
    float v0 = (erow[t] > 0) ? e : NEG_INF_;
    float e2 = si + s2b[t + 256];
    e2 = e2 > 0.f ? e2 : LRELU_ * e2;
    float v1 = (erow[t + 256] > 0) ? e2 : NEG_INF_;

    __shared__ float redm[4], reds[4];
    float m = fmaxf(v0, v1);
    for (int off = 32; off; off >>= 1) m = fmaxf(m, __shfl_xor(m, off));
    if ((t & 63) == 0) redm[t >> 6] = m;
    __syncthreads();
    m = fmaxf(fmaxf(redm[0], redm[1]), fmaxf(redm[2], redm[3]));
    float x0 = expf(v0 - m), x1 = expf(v1 - m);
    float s = x0 + x1;
    for (int off = 32; off; off >>= 1) s += __shfl_xor(s, off);
    if ((t & 63) == 0) reds[t >> 6] = s;
    __syncthreads();
    s = reds[0] + reds[1] + reds[2] + reds[3];
    float inv = 1.f / s;
    alpha[(long)row * N_ + t]       = f2bf(x0 * inv);
    alpha[(long)row * N_ + t + 256] = f2bf(x1 * inv);
}

// ============ attention softmax (f32 in-place, additive int mask) ============
__global__ __launch_bounds__(256) void attn_softmax(float* __restrict__ S,
                                                    const int* __restrict__ mask)
{
    long row = blockIdx.x;                 // (b*H + h)*N + i
    int  b   = (int)(row >> 12);
    float*     p    = S + row * N_;
    const int* mrow = mask + (long)b * N_;
    int t = threadIdx.x;

    float v0 = p[t]       + (float)mrow[t]       * NEG_INF_;
    float v1 = p[t + 256] + (float)mrow[t + 256] * NEG_INF_;

    __shared__ float redm[4], reds[4];
    float m = fmaxf(v0, v1);
    for (int off = 32; off; off >>= 1) m = fmaxf(m, __shfl_xor(m, off));
    if ((t & 63) == 0) redm[t >> 6] = m;
    __syncthreads();
    m = fmaxf(fmaxf(redm[0], redm[1]), fmaxf(redm[2], redm[3]));
    float e0 = expf(v0 - m), e1 = expf(v1 - m);
    float s = e0 + e1;
    for (int off = 32; off; off >>= 1) s += __shfl_xor(s, off);
    if ((t & 63) == 0) reds[t >> 6] = s;
    __syncthreads();
    s = reds[0] + reds[1] + reds[2] + reds[3];
    float inv = 1.f / s;
    p[t]       = e0 * inv;
    p[t + 256] = e1 * inv;
}

// ============ fused residual-add LayerNorm -> f32 + bf16 =====================
__global__ __launch_bounds__(64) void ln_add(const float* __restrict__ x,
                                             const float* __restrict__ tm,
                                             const float* __restrict__ g,
                                             const float* __restrict__ bta,
                                             float* __restrict__ out,
                                             unsigned short* __restrict__ outb)
{
    long row  = blockIdx.x;
    int  lane = threadIdx.x;
    float4 xv = ((const float4*)(x + row * D_))[lane];
    float4 tv = ((const float4*)(tm + row * D_))[lane];
    float4 v = make_float4(xv.x + tv.x, xv.y + tv.y, xv.z + tv.z, xv.w + tv.w);
    float s = v.x + v.y + v.z + v.w;
    for (int off = 32; off; off >>= 1) s += __shfl_xor(s, off);
    float mean = s * (1.f / D_);
    float4 d = make_float4(v.x - mean, v.y - mean, v.z - mean, v.w - mean);
    float sq = d.x * d.x + d.y * d.y + d.z * d.z + d.w * d.w;
    for (int off = 32; off; off >>= 1) sq += __shfl_xor(sq, off);
    float rs = rsqrtf(sq * (1.f / D_) + 1e-6f);
    float4 gv = ((const float4*)g)[lane];
    float4 bv = ((const float4*)bta)[lane];
    float4 o = make_float4(d.x * rs * gv.x + bv.x, d.y * rs * gv.y + bv.y,
                           d.z * rs * gv.z + bv.z, d.w * rs * gv.w + bv.w);
    ((float4*)(out + row * D_))[lane] = o;
    ((ushort4*)(outb + row * D_))[lane] =
        make_ushort4(f2bf(o.x), f2bf(o.y), f2bf(o.z), f2bf(o.w));
}

// ============ x = x*sqrt(D) + positional encoding -> f32 + bf16 ==============
__global__ __launch_bounds__(256) void scale_pe(float* __restrict__ X,
                                                unsigned short* __restrict__ Xb)
{
    int row = blockIdx.x;            // b*N + n
    int n = row & (N_ - 1);
    int d = threadIdx.x;
    float expo = (float)(d & ~1) * (1.0f / D_);
    float inv  = powf(10000.0f, -expo);
    float ang  = (float)n * inv;
    float pe   = (d & 1) ? cosf(ang) : sinf(ang);
    long idx = (long)row * D_ + d;
    float v = X[idx] * 16.0f + pe;
    X[idx]  = v;
    Xb[idx] = f2bf(v);
}

__global__ __launch_bounds__(256) void copy_f4(const float4* __restrict__ src,
                                               float4* __restrict__ dst, long n4)
{
    long i = (long)blockIdx.x * 256 + threadIdx.x;
    if (i < n4) dst[i] = src[i];
}

// ============ driver =========================================================
extern "C" void kernel_launch(void* const* d_in, const int* in_sizes, int n_in,
                              void* d_out, int out_size, void* d_ws, size_t ws_size,
                              hipStream_t stream)
{
    const int*   node  = (const int*)d_in[0];
    const int*   edge  = (const int*)d_in[1];
    const int*   mask  = (const int*)d_in[2];
    const float* embed = (const float*)d_in[4];
    const float* Wg    = (const float*)d_in[5];
    const float* a1    = (const float*)d_in[6];
    const float* a2    = (const float*)d_in[7];
    const float* Wq    = (const float*)d_in[8];
    const float* bq    = (const float*)d_in[9];
    const float* Wk    = (const float*)d_in[10];
    const float* bk    = (const float*)d_in[11];
    const float* Wv    = (const float*)d_in[12];
    const float* bv    = (const float*)d_in[13];
    const float* Wo    = (const float*)d_in[14];
    const float* bo    = (const float*)d_in[15];
    const float* W1    = (const float*)d_in[16];
    const float* b1    = (const float*)d_in[17];
    const float* W2    = (const float*)d_in[18];
    const float* b2    = (const float*)d_in[19];
    const float* ln1g  = (const float*)d_in[20];
    const float* ln1b  = (const float*)d_in[21];
    const float* ln2g  = (const float*)d_in[22];
    const float* ln2b  = (const float*)d_in[23];

    const long XSZ = (long)B_ * N_ * D_;          // 2,097,152 elements
    const int  MR  = B_ * N_;                     // 8192 tokens
    float* outx = (float*)d_out;
    float* ATT  = outx + XSZ;                     // [B,H,N,N] f32 (scratch + final attn)

    // ---- workspace layout (~41 MB) ----
    float*          X   = (float*)d_ws;                       // 8 MB
    unsigned short* Xb  = (unsigned short*)(X + XSZ);         // 4 MB
    float*          Hb  = (float*)(Xb + XSZ);                 // 8 MB (f32 temp)
    unsigned short* alphab = (unsigned short*)Hb;             // GAT alpha aliases Hb
    unsigned short* Qb  = (unsigned short*)(Hb + XSZ);        // 4 MB
    unsigned short* Kb  = Qb + XSZ;                           // 4 MB
    unsigned short* VT  = Kb + XSZ;                           // 4 MB ([D][B*N])
    unsigned short* Ob  = VT + XSZ;                           // 4 MB
    unsigned short* Fb  = Qb;                                 // FFN hidden aliases Q..O (16 MB)
    unsigned short* hT  = Qb;                                 // GAT h^T aliases Qb
    float* S1 = (float*)(Ob + XSZ);
    float* S2 = S1 + MR;
    unsigned short* WgT = (unsigned short*)(S2 + MR);
    unsigned short* WqT = WgT + 65536;
    unsigned short* WkT = WqT + 2 * 65536;
    unsigned short* WvT = WkT + 2 * 65536;
    unsigned short* WoT = WvT + 2 * 65536;
    unsigned short* W1T = WoT + 2 * 65536;      // [1024][256] per layer
    unsigned short* W2T = W1T + 2 * 262144;     // [256][1024] per layer

    // ---- convert + transpose all weights to bf16 ----
    ConvJobs j;
    j.src[0] = Wg;  j.dst[0] = WgT;  j.R[0] = 256;  j.C[0] = 256;
    for (int l = 0; l < 2; l++) {
        j.src[1 + l] = Wq + l * 65536;  j.dst[1 + l] = WqT + l * 65536;  j.R[1+l] = 256;  j.C[1+l] = 256;
        j.src[3 + l] = Wk + l * 65536;  j.dst[3 + l] = WkT + l * 65536;  j.R[3+l] = 256;  j.C[3+l] = 256;
        j.src[5 + l] = Wv + l * 65536;  j.dst[5 + l] = WvT + l * 65536;  j.R[5+l] = 256;  j.C[5+l] = 256;
        j.src[7 + l] = Wo + l * 65536;  j.dst[7 + l] = WoT + l * 65536;  j.R[7+l] = 256;  j.C[7+l] = 256;
        j.src[9 + l] = W1 + l * 262144; j.dst[9 + l] = W1T + l * 262144; j.R[9+l] = 256;  j.C[9+l] = 1024;
        j.src[11+ l] = W2 + l * 262144; j.dst[11+ l] = W2T + l * 262144; j.R[11+l]= 1024; j.C[11+l]= 256;
    }
    conv_transpose<<<dim3(16, 16, 13), 256, 0, stream>>>(j);

    // ---- embedding ----
    gather_embed<<<MR, 64, 0, stream>>>(node, embed, X, Xb);

    // ---- GAT hops ----
    for (int hop = 0; hop < 2; hop++) {
        // hT = (Xb @ Wg)^T : bf16 [256][8192]
        mfma_gemm<128,128,2,2,false><<<dim3(2, 64, 1), 256, 0, stream>>>(
            Xb, WgT, nullptr, nullptr, hT, 1,
            256, 256, 256, MR, 1, 0,0, 0,0, 0,0, 1.f, 0);
        gat_s12T<<<32, 256, 0, stream>>>(hT, a1, a2, S1, S2);
        gat_alpha<<<MR, 256, 0, stream>>>(S1, S2, edge, alphab);
        // X = elu(alpha @ h): A=alphab[b] (512x512), Bt=hT cols b*512.. (256x512)
        mfma_gemm<128,128,2,2,false><<<dim3(2, 4, 16), 256, 0, stream>>>(
            alphab, hT, nullptr, X, Xb, 0,
            512, 512, MR, 256, 1,
            (long)N_*N_, 0, (long)N_, 0, (long)N_*D_, 0, 1.f, 2);
    }

    // ---- x = x*sqrt(D) + pe ----
    scale_pe<<<MR, 256, 0, stream>>>(X, Xb);

    const float rscale = 0.17677669529663687f;    // 1/sqrt(32)
    for (int l = 0; l < L_; l++) {
        // Q, K: bf16 [8192][256]; V: transposed bf16 [256][8192]
        mfma_gemm<128,128,2,2,false><<<dim3(2, 64, 1), 256, 0, stream>>>(
            Xb, WqT + l * 65536, bq + l * D_, nullptr, Qb, 0,
            256, 256, 256, 256, 1, 0,0, 0,0, 0,0, 1.f, 0);
        mfma_gemm<128,128,2,2,false><<<dim3(2, 64, 1), 256, 0, stream>>>(
            Xb, WkT + l * 65536, bk + l * D_, nullptr, Kb, 0,
            256, 256, 256, 256, 1, 0,0, 0,0, 0,0, 1.f, 0);
        mfma_gemm<128,128,2,2,false><<<dim3(2, 64, 1), 256, 0, stream>>>(
            Xb, WvT + l * 65536, bv + l * D_, nullptr, VT, 1,
            256, 256, 256, MR, 1, 0,0, 0,0, 0,0, 1.f, 0);

        // scores = Q @ K^T * rscale -> ATT f32   (batch B*H, NT form, K=32)
        mfma_gemm<128,128,2,2,false><<<dim3(4, 4, B_ * H_), 256, 0, stream>>>(
            Qb, Kb, nullptr, ATT, nullptr, 0,
            32, 256, 256, 512, H_,
            (long)N_*D_, (long)DH_, (long)N_*D_, (long)DH_,
            (long)H_*N_*N_, (long)N_*N_, rscale, 0);

        attn_softmax<<<B_ * H_ * N_, 256, 0, stream>>>(ATT, mask);

        // O = attn @ V : A = ATT f32 (converted), Bt = VT rows h*32.., N=32
        mfma_gemm<128,32,4,1,true><<<dim3(1, 4, B_ * H_), 256, 0, stream>>>(
            ATT, VT, nullptr, nullptr, Ob, 0,
            512, 512, MR, 256, H_,
            (long)H_*N_*N_, (long)N_*N_, (long)N_, (long)DH_*MR,
            (long)N_*D_, (long)DH_, 1.f, 0);

        // Hb = O @ Wo + bo ; X = LN(X + Hb)
        mfma_gemm<128,128,2,2,false><<<dim3(2, 64, 1), 256, 0, stream>>>(
            Ob, WoT + l * 65536, bo + l * D_, Hb, nullptr, 0,
            256, 256, 256, 256, 1, 0,0, 0,0, 0,0, 1.f, 0);
        ln_add<<<MR, 64, 0, stream>>>(X, Hb, ln1g + l * D_, ln1b + l * D_, X, Xb);

        // F = relu(X @ W1 + b1) bf16 ; Hb = F @ W2 + b2 ; X = LN(X + Hb)
        mfma_gemm<128,128,2,2,false><<<dim3(8, 64, 1), 256, 0, stream>>>(
            Xb, W1T + l * 262144, b1 + l * DFF_, nullptr, Fb, 0,
            256, 256, 256, 1024, 1, 0,0, 0,0, 0,0, 1.f, 1);
        mfma_gemm<128,128,2,2,false><<<dim3(2, 64, 1), 256, 0, stream>>>(
            Fb, W2T + l * 262144, b2 + l * D_, Hb, nullptr, 0,
            1024, 1024, 1024, 256, 1, 0,0, 0,0, 0,0, 1.f, 0);
        ln_add<<<MR, 64, 0, stream>>>(X, Hb, ln2g + l * D_, ln2b + l * D_, X, Xb);
    }

    // ---- write x output ----
    long n4 = XSZ / 4;
    copy_f4<<<(unsigned)((n4 + 255) / 256), 256, 0, stream>>>((const float4*)X,
                                                              (float4*)outx, n4);
}

// Round 3
// 597.909 us; speedup vs baseline: 3.6975x; 1.2802x over previous
//
#include <hip/hip_runtime.h>
#include <math.h>

#define B_    16
#define N_    512
#define D_    256
#define H_    8
#define DH_   32
#define DFF_  1024
#define L_    2
#define NEG_INF_ (-1e9f)
#define LRELU_ 0.2f

typedef __attribute__((ext_vector_type(8))) short bf8_t;
typedef __attribute__((ext_vector_type(8))) unsigned short us8;
typedef __attribute__((ext_vector_type(4))) float f4_t;

__device__ __forceinline__ unsigned short f2bf(float f) {
    union { float f; unsigned u; } v; v.f = f;
    unsigned r = v.u + 0x7FFF + ((v.u >> 16) & 1);
    return (unsigned short)(r >> 16);
}
__device__ __forceinline__ float bf2f(unsigned short h) {
    union { unsigned u; float f; } v; v.u = ((unsigned)h) << 16;
    return v.f;
}

__device__ __forceinline__ void gl_lds16(const void* g, void* l) {
    __builtin_amdgcn_global_load_lds(
        (const __attribute__((address_space(1))) unsigned int*)g,
        (__attribute__((address_space(3))) unsigned int*)l, 16, 0, 0);
}

// ============ bf16 MFMA GEMM: C = act(scale * A @ Bt^T + bias) ==============
// A: [M x K] bf16 row-major; Bt: [N x K] bf16 row-major (k contiguous)
// out: Cf (f32) and/or Ch (bf16); trans=1 -> Ch[col*ldc + row] (bf16 only)
template <int BM, int BN, int WROWS, int WCOLS>
__global__ __launch_bounds__(256) void mfma_gemm(
    const unsigned short* __restrict__ Ag, const unsigned short* __restrict__ Btg,
    const float* __restrict__ bias,
    float* __restrict__ Cfg, unsigned short* __restrict__ Chg, int trans,
    int K, int lda, int ldb, int ldc,
    int inner, long sAo, long sAi, long sBo, long sBi, long sCo, long sCi,
    float scale, int act)
{
    constexpr int TM = BM / WROWS, TN = BN / WCOLS;
    constexpr int MT = TM / 16, NT = TN / 16;

    int z  = blockIdx.z;
    int zo = z / inner;
    int zi = z - zo * inner;
    const unsigned short* Ab = Ag + (long)zo * sAo + (long)zi * sAi;
    const unsigned short* Bt = Btg + (long)zo * sBo + (long)zi * sBi;
    long co = (long)zo * sCo + (long)zi * sCi;

    int bm = blockIdx.y * BM;
    int bn = blockIdx.x * BN;
    int tid  = threadIdx.x;
    int lane = tid & 63;
    int w    = tid >> 6;
    int wr   = w / WCOLS, wc = w - wr * WCOLS;

    __shared__ unsigned short As[BM * 32];
    __shared__ unsigned short Bs[BN * 32];

    f4_t acc[MT][NT] = {};

    int lrow = lane & 15;
    int koff = (lane >> 4) * 8;

    for (int k0 = 0; k0 < K; k0 += 32) {
#pragma unroll
        for (int t = w; t < BM / 16; t += 4) {
            int s = t * 512 + lane * 8;
            int r = s >> 5, c = s & 31;
            gl_lds16(Ab + (long)(bm + r) * lda + k0 + c, &As[t * 512]);
        }
#pragma unroll
        for (int t = w; t < BN / 16; t += 4) {
            int s = t * 512 + lane * 8;
            int r = s >> 5, c = s & 31;
            gl_lds16(Bt + (long)(bn + r) * ldb + k0 + c, &Bs[t * 512]);
        }
        __syncthreads();

        bf8_t af[MT], bfr[NT];
#pragma unroll
        for (int mi = 0; mi < MT; mi++)
            af[mi] = *(const bf8_t*)&As[(wr * TM + mi * 16 + lrow) * 32 + koff];
#pragma unroll
        for (int ni = 0; ni < NT; ni++)
            bfr[ni] = *(const bf8_t*)&Bs[(wc * TN + ni * 16 + lrow) * 32 + koff];
#pragma unroll
        for (int mi = 0; mi < MT; mi++)
#pragma unroll
            for (int ni = 0; ni < NT; ni++)
                acc[mi][ni] = __builtin_amdgcn_mfma_f32_16x16x32_bf16(
                    af[mi], bfr[ni], acc[mi][ni], 0, 0, 0);
        __syncthreads();
    }

#pragma unroll
    for (int mi = 0; mi < MT; mi++) {
#pragma unroll
        for (int ni = 0; ni < NT; ni++) {
            int row0 = bm + wr * TM + mi * 16 + (lane >> 4) * 4;
            int col  = bn + wc * TN + ni * 16 + (lane & 15);
            float bv = bias ? bias[col] : 0.f;
            float vv[4];
#pragma unroll
            for (int r = 0; r < 4; r++) {
                float v = acc[mi][ni][r] * scale + bv;
                if (act == 1) v = fmaxf(v, 0.f);
                else if (act == 2) v = v > 0.f ? v : (__expf(v) - 1.f);
                vv[r] = v;
            }
            if (trans) {
                ushort4 u = make_ushort4(f2bf(vv[0]), f2bf(vv[1]), f2bf(vv[2]), f2bf(vv[3]));
                *(ushort4*)&Chg[co + (long)col * ldc + row0] = u;
            } else {
                if (Cfg) {
#pragma unroll
                    for (int r = 0; r < 4; r++)
                        Cfg[co + (long)(row0 + r) * ldc + col] = vv[r];
                }
                if (Chg) {
#pragma unroll
                    for (int r = 0; r < 4; r++)
                        Chg[co + (long)(row0 + r) * ldc + col] = f2bf(vv[r]);
                }
            }
        }
    }
}

// ============ fused attention: scores -> mask -> softmax -> PV ==============
// QKV: [B*N][768] bf16 (Q cols 0..255, K 256..511, V 512..767)
// one workgroup = (b,h) x 64-query tile; 4 waves x 16 rows.
template <bool WRITE_ATTN>
__global__ __launch_bounds__(256) void attn_fused(
    const unsigned short* __restrict__ QKV,
    const int* __restrict__ mask,
    float* __restrict__ attn_out,            // [B,H,N,N] f32
    unsigned short* __restrict__ Ob)         // [B*N][256] bf16
{
    int bh = blockIdx.x;
    int b  = bh >> 3, h = bh & 7;
    int q0 = blockIdx.y * 64;
    int tid  = threadIdx.x;
    int lane = tid & 63, w = tid >> 6;
    int lrow = lane & 15, quad = lane >> 4;

    __shared__ unsigned short Ks[512 * 40];   // K tile, row stride 40 (padded)
    __shared__ unsigned short Vs[32 * 136];   // V^T chunk, row stride 136
    __shared__ float maskf[512];
    unsigned short* Ps = Ks;                  // P staging aliases dead K tile

    const long tokbase = (long)b * N_;

    // ---- stage K tile [512][32] ----
#pragma unroll
    for (int i = 0; i < 8; i++) {
        int idx = tid + i * 256;
        int row = idx >> 2, seg = idx & 3;
        us8 v = *(const us8*)&QKV[(tokbase + row) * 768 + 256 + h * 32 + seg * 8];
        *(us8*)&Ks[row * 40 + seg * 8] = v;
    }
    maskf[tid]       = (float)mask[b * N_ + tid] * NEG_INF_;
    maskf[tid + 256] = (float)mask[b * N_ + tid + 256] * NEG_INF_;

    // ---- Q fragment (A-operand, one per wave-row-set) ----
    bf8_t aq = *(const bf8_t*)&QKV[(tokbase + q0 + w * 16 + lrow) * 768 + h * 32 + quad * 8];
    __syncthreads();

    // ---- S = Q @ K^T (16 rows x 512 cols per wave) ----
    f4_t acc[32];
    f4_t zero = {0.f, 0.f, 0.f, 0.f};
#pragma unroll
    for (int ni = 0; ni < 32; ni++) {
        bf8_t bk = *(const bf8_t*)&Ks[(ni * 16 + lrow) * 40 + quad * 8];
        acc[ni] = __builtin_amdgcn_mfma_f32_16x16x32_bf16(aq, bk, zero, 0, 0, 0);
    }

    // ---- scale + mask + softmax (rows live in (quad, reg)) ----
    const float rscale = 0.17677669529663687f;   // 1/sqrt(32)
    float mr[4] = {-3e38f, -3e38f, -3e38f, -3e38f};
#pragma unroll
    for (int ni = 0; ni < 32; ni++) {
        float mk = maskf[ni * 16 + lrow];
#pragma unroll
        for (int r = 0; r < 4; r++) {
            float v = acc[ni][r] * rscale + mk;
            acc[ni][r] = v;
            mr[r] = fmaxf(mr[r], v);
        }
    }
#pragma unroll
    for (int r = 0; r < 4; r++) {
        mr[r] = fmaxf(mr[r], __shfl_xor(mr[r], 1));
        mr[r] = fmaxf(mr[r], __shfl_xor(mr[r], 2));
        mr[r] = fmaxf(mr[r], __shfl_xor(mr[r], 4));
        mr[r] = fmaxf(mr[r], __shfl_xor(mr[r], 8));
    }
    float sr[4] = {0.f, 0.f, 0.f, 0.f};
#pragma unroll
    for (int ni = 0; ni < 32; ni++) {
#pragma unroll
        for (int r = 0; r < 4; r++) {
            float p = __expf(acc[ni][r] - mr[r]);
            acc[ni][r] = p;
            sr[r] += p;
        }
    }
#pragma unroll
    for (int r = 0; r < 4; r++) {
        sr[r] += __shfl_xor(sr[r], 1);
        sr[r] += __shfl_xor(sr[r], 2);
        sr[r] += __shfl_xor(sr[r], 4);
        sr[r] += __shfl_xor(sr[r], 8);
        sr[r] = 1.f / sr[r];
    }
#pragma unroll
    for (int ni = 0; ni < 32; ni++)
#pragma unroll
        for (int r = 0; r < 4; r++)
            acc[ni][r] *= sr[r];

    if (WRITE_ATTN) {
#pragma unroll
        for (int ni = 0; ni < 32; ni++) {
#pragma unroll
            for (int r = 0; r < 4; r++)
                attn_out[((long)bh * N_ + q0 + w * 16 + quad * 4 + r) * N_ + ni * 16 + lrow]
                    = acc[ni][r];
        }
    }

    // ---- O = P @ V, chunks of 128 keys ----
    f4_t oacc[2] = {{0.f,0.f,0.f,0.f}, {0.f,0.f,0.f,0.f}};
    for (int c = 0; c < 4; c++) {
        __syncthreads();   // prev chunk MFMA done (and, at c=0, all Ks reads done)
        {   // stage V^T chunk: Vs[d][kk] = V[c*128+kk][d]
            int kk = tid >> 1, dseg = (tid & 1) * 16;
            const unsigned short* src =
                &QKV[(tokbase + c * 128 + kk) * 768 + 512 + h * 32 + dseg];
            us8 v0 = *(const us8*)src;
            us8 v1 = *(const us8*)(src + 8);
#pragma unroll
            for (int jj = 0; jj < 8; jj++) {
                Vs[(dseg + jj) * 136 + kk]     = v0[jj];
                Vs[(dseg + 8 + jj) * 136 + kk] = v1[jj];
            }
        }
        // write this wave's P chunk (wave-private region, C-layout -> A-layout)
#pragma unroll
        for (int ni = 0; ni < 8; ni++) {
            int nn = c * 8 + ni;
#pragma unroll
            for (int r = 0; r < 4; r++)
                Ps[w * 2176 + (quad * 4 + r) * 136 + ni * 16 + lrow] = f2bf(acc[nn][r]);
        }
        __syncthreads();
#pragma unroll
        for (int k8 = 0; k8 < 4; k8++) {
            bf8_t ap = *(const bf8_t*)&Ps[w * 2176 + lrow * 136 + k8 * 32 + quad * 8];
#pragma unroll
            for (int t = 0; t < 2; t++) {
                bf8_t bvf = *(const bf8_t*)&Vs[(t * 16 + lrow) * 136 + k8 * 32 + quad * 8];
                oacc[t] = __builtin_amdgcn_mfma_f32_16x16x32_bf16(ap, bvf, oacc[t], 0, 0, 0);
            }
        }
    }

#pragma unroll
    for (int t = 0; t < 2; t++)
#pragma unroll
        for (int r = 0; r < 4; r++)
            Ob[(tokbase + q0 + w * 16 + quad * 4 + r) * 256 + h * 32 + t * 16 + lrow]
                = f2bf(oacc[t][r]);
}

// ============ weight transpose + f32->bf16 conversion ========================
struct ConvJobs {
    const float* src[13];
    unsigned short* dst[13];
    int R[13];
    int C[13];
};

__global__ __launch_bounds__(256) void conv_transpose(ConvJobs j)
{
    int z = blockIdx.z;
    int R = j.R[z], C = j.C[z];
    int r0 = blockIdx.y * 64, c0 = blockIdx.x * 64;
    if (r0 >= R || c0 >= C) return;
    __shared__ float t[64][65];
    const float* src = j.src[z];
    unsigned short* dst = j.dst[z];
    int tx = threadIdx.x & 63, ty = threadIdx.x >> 6;
#pragma unroll
    for (int i = 0; i < 16; i++) {
        int r = ty + i * 4;
        t[r][tx] = src[(long)(r0 + r) * C + c0 + tx];
    }
    __syncthreads();
#pragma unroll
    for (int i = 0; i < 16; i++) {
        int c = ty + i * 4;
        dst[(long)(c0 + c) * R + r0 + tx] = f2bf(t[tx][c]);
    }
}

// ============ pack bq|bk|bv -> bc [L][768] ===================================
__global__ __launch_bounds__(256) void pack_bias(const float* __restrict__ bq,
                                                 const float* __restrict__ bk,
                                                 const float* __restrict__ bv,
                                                 float* __restrict__ bc)
{
    int i = blockIdx.x * 256 + threadIdx.x;     // 0..1535
    int l = i / 768, c = i - l * 768;
    float v = (c < 256) ? bq[l * 256 + c]
            : (c < 512) ? bk[l * 256 + c - 256]
                        : bv[l * 256 + c - 512];
    bc[i] = v;
}

// ============ embedding gather -> X f32 + Xb bf16 ============================
__global__ __launch_bounds__(64) void gather_embed(const int* __restrict__ idx,
                                                   const float* __restrict__ embed,
                                                   float* __restrict__ X,
                                                   unsigned short* __restrict__ Xb)
{
    int row = blockIdx.x;
    int id  = idx[row];
    float4 v = ((const float4*)(embed + (long)id * D_))[threadIdx.x];
    ((float4*)(X + (long)row * D_))[threadIdx.x] = v;
    ((ushort4*)(Xb + (long)row * D_))[threadIdx.x] =
        make_ushort4(f2bf(v.x), f2bf(v.y), f2bf(v.z), f2bf(v.w));
}

// ============ GAT s1/s2 from transposed h (bf16 [D][B*N]) ====================
__global__ __launch_bounds__(256) void gat_s12T(const unsigned short* __restrict__ hT,
                                                const float* __restrict__ a1,
                                                const float* __restrict__ a2,
                                                float* __restrict__ s1,
                                                float* __restrict__ s2)
{
    int j = blockIdx.x * 256 + threadIdx.x;
    float d1 = 0.f, d2 = 0.f;
    for (int d = 0; d < D_; d++) {
        float hv = bf2f(hT[(long)d * (B_ * N_) + j]);
        d1 += hv * a1[d];
        d2 += hv * a2[d];
    }
    s1[j] = d1;
    s2[j] = d2;
}

// ============ GAT softmax row -> bf16 alpha ==================================
__global__ __launch_bounds__(256) void gat_alpha(const float* __restrict__ s1,
                                                 const float* __restrict__ s2,
                                                 const int* __restrict__ edges,
                                                 unsigned short* __restrict__ alpha)
{
    int row = blockIdx.x;
    int b   = row >> 9;
    const int*   erow = edges + (long)row * N_;
    const float* s2b  = s2 + (long)b * N_;
    float si = s1[row];
    int t = threadIdx.x;

    float e  = si + s2b[t];
    e = e > 0.f ? e : LRELU_ * e;
    float v0 = (erow[t] > 0) ? e : NEG_INF_;
    float e2 = si + s2b[t + 256];
    e2 = e2 > 0.f ? e2 : LRELU_ * e2;
    float v1 = (erow[t + 256] > 0) ? e2 : NEG_INF_;

    __shared__ float redm[4], reds[4];
    float m = fmaxf(v0, v1);
    for (int off = 32; off; off >>= 1) m = fmaxf(m, __shfl_xor(m, off));
    if ((t & 63) == 0) redm[t >> 6] = m;
    __syncthreads();
    m = fmaxf(fmaxf(redm[0], redm[1]), fmaxf(redm[2], redm[3]));
    float x0 = __expf(v0 - m), x1 = __expf(v1 - m);
    float s = x0 + x1;
    for (int off = 32; off; off >>= 1) s += __shfl_xor(s, off);
    if ((t & 63) == 0) reds[t >> 6] = s;
    __syncthreads();
    s = reds[0] + reds[1] + reds[2] + reds[3];
    float inv = 1.f / s;
    alpha[(long)row * N_ + t]       = f2bf(x0 * inv);
    alpha[(long)row * N_ + t + 256] = f2bf(x1 * inv);
}

// ============ fused residual-add LayerNorm -> f32 + bf16 =====================
__global__ __launch_bounds__(64) void ln_add(const float* __restrict__ x,
                                             const float* __restrict__ tm,
                                             const float* __restrict__ g,
                                             const float* __restrict__ bta,
                                             float* __restrict__ out,
                                             unsigned short* __restrict__ outb)
{
    long row  = blockIdx.x;
    int  lane = threadIdx.x;
    float4 xv = ((const float4*)(x + row * D_))[lane];
    float4 tv = ((const float4*)(tm + row * D_))[lane];
    float4 v = make_float4(xv.x + tv.x, xv.y + tv.y, xv.z + tv.z, xv.w + tv.w);
    float s = v.x + v.y + v.z + v.w;
    for (int off = 32; off; off >>= 1) s += __shfl_xor(s, off);
    float mean = s * (1.f / D_);
    float4 d = make_float4(v.x - mean, v.y - mean, v.z - mean, v.w - mean);
    float sq = d.x * d.x + d.y * d.y + d.z * d.z + d.w * d.w;
    for (int off = 32; off; off >>= 1) sq += __shfl_xor(sq, off);
    float rs = rsqrtf(sq * (1.f / D_) + 1e-6f);
    float4 gv = ((const float4*)g)[lane];
    float4 bv = ((const float4*)bta)[lane];
    float4 o = make_float4(d.x * rs * gv.x + bv.x, d.y * rs * gv.y + bv.y,
                           d.z * rs * gv.z + bv.z, d.w * rs * gv.w + bv.w);
    ((float4*)(out + row * D_))[lane] = o;
    ((ushort4*)(outb + row * D_))[lane] =
        make_ushort4(f2bf(o.x), f2bf(o.y), f2bf(o.z), f2bf(o.w));
}

// ============ x = x*sqrt(D) + positional encoding -> f32 + bf16 ==============
__global__ __launch_bounds__(256) void scale_pe(float* __restrict__ X,
                                                unsigned short* __restrict__ Xb)
{
    int row = blockIdx.x;
    int n = row & (N_ - 1);
    int d = threadIdx.x;
    float expo = (float)(d & ~1) * (1.0f / D_);
    float inv  = powf(10000.0f, -expo);
    float ang  = (float)n * inv;
    float pe   = (d & 1) ? cosf(ang) : sinf(ang);
    long idx = (long)row * D_ + d;
    float v = X[idx] * 16.0f + pe;
    X[idx]  = v;
    Xb[idx] = f2bf(v);
}

__global__ __launch_bounds__(256) void copy_f4(const float4* __restrict__ src,
                                               float4* __restrict__ dst, long n4)
{
    long i = (long)blockIdx.x * 256 + threadIdx.x;
    if (i < n4) dst[i] = src[i];
}

// ============ driver =========================================================
extern "C" void kernel_launch(void* const* d_in, const int* in_sizes, int n_in,
                              void* d_out, int out_size, void* d_ws, size_t ws_size,
                              hipStream_t stream)
{
    const int*   node  = (const int*)d_in[0];
    const int*   edge  = (const int*)d_in[1];
    const int*   mask  = (const int*)d_in[2];
    const float* embed = (const float*)d_in[4];
    const float* Wg    = (const float*)d_in[5];
    const float* a1    = (const float*)d_in[6];
    const float* a2    = (const float*)d_in[7];
    const float* Wq    = (const float*)d_in[8];
    const float* bq    = (const float*)d_in[9];
    const float* Wk    = (const float*)d_in[10];
    const float* bk    = (const float*)d_in[11];
    const float* Wv    = (const float*)d_in[12];
    const float* bv    = (const float*)d_in[13];
    const float* Wo    = (const float*)d_in[14];
    const float* bo    = (const float*)d_in[15];
    const float* W1    = (const float*)d_in[16];
    const float* b1    = (const float*)d_in[17];
    const float* W2    = (const float*)d_in[18];
    const float* b2    = (const float*)d_in[19];
    const float* ln1g  = (const float*)d_in[20];
    const float* ln1b  = (const float*)d_in[21];
    const float* ln2g  = (const float*)d_in[22];
    const float* ln2b  = (const float*)d_in[23];

    const long XSZ = (long)B_ * N_ * D_;          // 2,097,152
    const int  MR  = B_ * N_;                     // 8192
    float* outx = (float*)d_out;
    float* ATT  = outx + XSZ;                     // [B,H,N,N] f32 (final attn)

    // ---- workspace layout ----
    float*          X    = (float*)d_ws;
    unsigned short* Xb   = (unsigned short*)(X + XSZ);
    float*          Hb   = (float*)(Xb + XSZ);
    unsigned short* alphab = (unsigned short*)Hb;             // GAT alpha aliases Hb
    unsigned short* QKVb = (unsigned short*)(Hb + XSZ);       // [8192][768] bf16
    unsigned short* hT   = QKVb;                              // GAT h^T aliases QKV
    unsigned short* Ob   = QKVb + (long)MR * 768;
    unsigned short* Fb   = Ob + XSZ;                          // [8192][1024] bf16
    float* S1 = (float*)(Fb + (long)MR * DFF_);
    float* S2 = S1 + MR;
    unsigned short* WgT = (unsigned short*)(S2 + MR);         // [256][256]
    unsigned short* Wc  = WgT + 65536;                        // [L][768][256]
    unsigned short* WoT = Wc + 2 * 768 * 256;                 // [L][256][256]
    unsigned short* W1T = WoT + 2 * 65536;                    // [L][1024][256]
    unsigned short* W2T = W1T + 2 * 262144;                   // [L][256][1024]
    float*          bc  = (float*)(W2T + 2 * 262144);         // [L][768]

    // ---- convert + transpose all weights to bf16 ----
    ConvJobs j;
    j.src[0] = Wg;  j.dst[0] = WgT;  j.R[0] = 256;  j.C[0] = 256;
    for (int l = 0; l < 2; l++) {
        j.src[1 + l] = Wq + l * 65536;  j.dst[1 + l] = Wc + l * 196608;           j.R[1+l] = 256;  j.C[1+l] = 256;
        j.src[3 + l] = Wk + l * 65536;  j.dst[3 + l] = Wc + l * 196608 + 65536;   j.R[3+l] = 256;  j.C[3+l] = 256;
        j.src[5 + l] = Wv + l * 65536;  j.dst[5 + l] = Wc + l * 196608 + 131072;  j.R[5+l] = 256;  j.C[5+l] = 256;
        j.src[7 + l] = Wo + l * 65536;  j.dst[7 + l] = WoT + l * 65536;           j.R[7+l] = 256;  j.C[7+l] = 256;
        j.src[9 + l] = W1 + l * 262144; j.dst[9 + l] = W1T + l * 262144;          j.R[9+l] = 256;  j.C[9+l] = 1024;
        j.src[11+ l] = W2 + l * 262144; j.dst[11+ l] = W2T + l * 262144;          j.R[11+l]= 1024; j.C[11+l]= 256;
    }
    conv_transpose<<<dim3(16, 16, 13), 256, 0, stream>>>(j);
    pack_bias<<<6, 256, 0, stream>>>(bq, bk, bv, bc);

    // ---- embedding ----
    gather_embed<<<MR, 64, 0, stream>>>(node, embed, X, Xb);

    // ---- GAT hops ----
    for (int hop = 0; hop < 2; hop++) {
        mfma_gemm<128,128,2,2><<<dim3(2, 64, 1), 256, 0, stream>>>(
            Xb, WgT, nullptr, nullptr, hT, 1,
            256, 256, 256, MR, 1, 0,0, 0,0, 0,0, 1.f, 0);
        gat_s12T<<<32, 256, 0, stream>>>(hT, a1, a2, S1, S2);
        gat_alpha<<<MR, 256, 0, stream>>>(S1, S2, edge, alphab);
        mfma_gemm<128,128,2,2><<<dim3(2, 4, 16), 256, 0, stream>>>(
            alphab, hT, nullptr, X, Xb, 0,
            512, 512, MR, 256, 1,
            (long)N_*N_, 0, (long)N_, 0, (long)N_*D_, 0, 1.f, 2);
    }

    // ---- x = x*sqrt(D) + pe ----
    scale_pe<<<MR, 256, 0, stream>>>(X, Xb);

    for (int l = 0; l < L_; l++) {
        // QKV combined projection: [8192][768] bf16
        mfma_gemm<128,128,2,2><<<dim3(6, 64, 1), 256, 0, stream>>>(
            Xb, Wc + l * 196608, bc + l * 768, nullptr, QKVb, 0,
            256, 256, 256, 768, 1, 0,0, 0,0, 0,0, 1.f, 0);

        // fused attention (layer 1 also writes the attn output matrix)
        if (l == L_ - 1)
            attn_fused<true><<<dim3(128, 8, 1), 256, 0, stream>>>(QKVb, mask, ATT, Ob);
        else
            attn_fused<false><<<dim3(128, 8, 1), 256, 0, stream>>>(QKVb, mask, nullptr, Ob);

        // Hb = O @ Wo + bo ; X = LN(X + Hb)
        mfma_gemm<128,128,2,2><<<dim3(2, 64, 1), 256, 0, stream>>>(
            Ob, WoT + l * 65536, bo + l * D_, Hb, nullptr, 0,
            256, 256, 256, 256, 1, 0,0, 0,0, 0,0, 1.f, 0);
        ln_add<<<MR, 64, 0, stream>>>(X, Hb, ln1g + l * D_, ln1b + l * D_, X, Xb);

        // F = relu(X @ W1 + b1) ; Hb = F @ W2 + b2 ; X = LN(X + Hb)
        mfma_gemm<128,128,2,2><<<dim3(8, 64, 1), 256, 0, stream>>>(
            Xb, W1T + l * 262144, b1 + l * DFF_, nullptr, Fb, 0,
            256, 256, 256, 1024, 1, 0,0, 0,0, 0,0, 1.f, 1);
        mfma_gemm<128,128,2,2><<<dim3(2, 64, 1), 256, 0, stream>>>(
            Fb, W2T + l * 262144, b2 + l * D_, Hb, nullptr, 0,
            1024, 1024, 1024, 256, 1, 0,0, 0,0, 0,0, 1.f, 0);
        ln_add<<<MR, 64, 0, stream>>>(X, Hb, ln2g + l * D_, ln2b + l * D_, X, Xb);
    }

    // ---- write x output ----
    long n4 = XSZ / 4;
    copy_f4<<<(unsigned)((n4 + 255) / 256), 256, 0, stream>>>((const float4*)X,
                                                              (float4*)outx, n4);
}